// Round 5
// baseline (530.820 us; speedup 1.0000x reference)
//
#include <hip/hip_runtime.h>
#include <math.h>

#define B_ 16
#define T_ 2048
#define H_ 1024
#define TPB 32   // t-rows per block in k1
#define KPB 8    // output rows per block in k3
#define K1REP 8  // MEASUREMENT: repeat K1 streaming body (idempotent)
#define K3REP 8  // MEASUREMENT: repeat K3 streaming body (idempotent)

typedef float f32x4_t __attribute__((ext_vector_type(4)));

__device__ __forceinline__ void ntstore4(float* p, float4 v) {
    f32x4_t w = { v.x, v.y, v.z, v.w };
    __builtin_nontemporal_store(w, (f32x4_t*)p);
}

// ---------------------------------------------------------------------------
// K1: alphas = sigmoid(sum_h relu(conv+bias+x) * lin_w + lin_b)
// MEASUREMENT ROUND: body repeated K1REP times (identical stores each rep).
// ---------------------------------------------------------------------------
__global__ __launch_bounds__(256) void k1_alphas(
    const float* __restrict__ hidden, const float* __restrict__ conv_w,
    const float* __restrict__ conv_b, const float* __restrict__ lin_w,
    const float* __restrict__ lin_b, float* __restrict__ alphas)
{
    const int tile = blockIdx.x & (T_ / TPB - 1);
    const int b    = blockIdx.x / (T_ / TPB);
    const int tid  = threadIdx.x;
    const int h0   = tid * 4;

    float w0[4], w1[4], w2[4];
    {
        const float4* cw = (const float4*)(conv_w + (size_t)h0 * 3);
        float4 c0 = cw[0], c1 = cw[1], c2 = cw[2];
        w0[0] = c0.x; w1[0] = c0.y; w2[0] = c0.z;
        w0[1] = c0.w; w1[1] = c1.x; w2[1] = c1.y;
        w0[2] = c1.z; w1[2] = c1.w; w2[2] = c2.x;
        w0[3] = c2.y; w1[3] = c2.z; w2[3] = c2.w;
    }
    const float4 cb = *(const float4*)(conv_b + h0);
    const float4 lw = *(const float4*)(lin_w + h0);
    const float  lb = lin_b[0];

    const size_t base = ((size_t)b * T_) * H_ + h0;
    const int t0 = tile * TPB;
    const float4 zero4 = make_float4(0.f, 0.f, 0.f, 0.f);

    __shared__ float lds[4][TPB];
    const int wave = tid >> 6;
    const int lane = tid & 63;

    #pragma unroll 1
    for (int rep = 0; rep < K1REP; ++rep) {
        float4 prev = (t0 > 0) ? *(const float4*)(hidden + base + (size_t)(t0 - 1) * H_)
                               : zero4;
        float4 curr = *(const float4*)(hidden + base + (size_t)t0 * H_);
        float4 buf0 = *(const float4*)(hidden + base + (size_t)(t0 + 1) * H_);
        float4 buf1 = *(const float4*)(hidden + base + (size_t)(t0 + 2) * H_);
        float4 buf2 = *(const float4*)(hidden + base + (size_t)(t0 + 3) * H_);
        float4 buf3 = *(const float4*)(hidden + base + (size_t)(t0 + 4) * H_);

        #pragma unroll
        for (int tt = 0; tt < TPB; ++tt) {
            float4 next;
            const int tp = t0 + tt + 5;
            switch (tt & 3) {
            case 0: next = buf0;
                    buf0 = (tp < T_) ? *(const float4*)(hidden + base + (size_t)tp * H_) : zero4;
                    break;
            case 1: next = buf1;
                    buf1 = (tp < T_) ? *(const float4*)(hidden + base + (size_t)tp * H_) : zero4;
                    break;
            case 2: next = buf2;
                    buf2 = (tp < T_) ? *(const float4*)(hidden + base + (size_t)tp * H_) : zero4;
                    break;
            default: next = buf3;
                    buf3 = (tp < T_) ? *(const float4*)(hidden + base + (size_t)tp * H_) : zero4;
                    break;
            }

            float p = 0.f, v;
            v = fmaf(w0[0], prev.x, fmaf(w1[0], curr.x, fmaf(w2[0], next.x, cb.x + curr.x)));
            p = fmaf(fmaxf(v, 0.f), lw.x, p);
            v = fmaf(w0[1], prev.y, fmaf(w1[1], curr.y, fmaf(w2[1], next.y, cb.y + curr.y)));
            p = fmaf(fmaxf(v, 0.f), lw.y, p);
            v = fmaf(w0[2], prev.z, fmaf(w1[2], curr.z, fmaf(w2[2], next.z, cb.z + curr.z)));
            p = fmaf(fmaxf(v, 0.f), lw.z, p);
            v = fmaf(w0[3], prev.w, fmaf(w1[3], curr.w, fmaf(w2[3], next.w, cb.w + curr.w)));
            p = fmaf(fmaxf(v, 0.f), lw.w, p);
            #pragma unroll
            for (int m = 32; m; m >>= 1) p += __shfl_xor(p, m);
            if (lane == 0) lds[wave][tt] = p;
            prev = curr; curr = next;
        }
        __syncthreads();
        if (tid < TPB) {
            float s = lds[0][tid] + lds[1][tid] + lds[2][tid] + lds[3][tid] + lb;
            alphas[(size_t)b * T_ + t0 + tid] = 1.f / (1.f + expf(-s));
        }
        __syncthreads();  // protect lds reuse across reps
        asm volatile("" ::: "memory");  // keep per-rep stores live/ordered
    }
}

// ---------------------------------------------------------------------------
// K2 (fused scan+coef): unchanged (x1).
// ---------------------------------------------------------------------------
__global__ __launch_bounds__(256) void k2_scan_coef(
    const float* __restrict__ alphas, float* __restrict__ fires,
    float* __restrict__ wgt,
    int* __restrict__ fire_pos, int* __restrict__ n_fires,
    float* __restrict__ cif_length, int Lpad)
{
    const int b = blockIdx.x;
    const int tid = threadIdx.x;
    const size_t base = (size_t)b * T_;

    __shared__ float sA[T_];
    __shared__ float sF[T_];

    {
        const int i = tid * 8;
        *(float4*)(sA + i)     = *(const float4*)(alphas + base + i);
        *(float4*)(sA + i + 4) = *(const float4*)(alphas + base + i + 4);
    }
    __syncthreads();

    if (tid == 0) {
        float I = 0.f;
        for (int t = 0; t < T_; t += 8) {
            #pragma unroll
            for (int j = 0; j < 8; ++j) {
                I += sA[t + j];
                sF[t + j] = I;
                I = __builtin_amdgcn_fractf(I);
            }
        }
    }
    __syncthreads();

    const int t0 = tid * 8;
    float a[8], f[8];
    #pragma unroll
    for (int j = 0; j < 8; ++j) { a[j] = sA[t0 + j]; f[j] = sF[t0 + j]; }
    const float fprev = (t0 == 0) ? 0.f : sF[t0 - 1];

    ntstore4(fires + base + t0,     make_float4(f[0], f[1], f[2], f[3]));
    ntstore4(fires + base + t0 + 4, make_float4(f[4], f[5], f[6], f[7]));

    float w[16];
    bool fr[8];
    float asum = 0.f;
    int cnt = 0;
    #pragma unroll
    for (int j = 0; j < 8; ++j) {
        float fp = (j == 0) ? fprev : f[j - 1];
        float Iprev = __builtin_amdgcn_fractf(fp);
        fr[j] = (f[j] >= 1.f);
        const float dist = 1.f - Iprev;
        const float cu = fr[j] ? dist : a[j];
        const float re = a[j] - cu;
        w[2 * j]     = cu;
        w[2 * j + 1] = fr[j] ? re : -1.f;
        cnt += fr[j] ? 1 : 0;
        asum += a[j];
    }
    {
        const size_t wb = ((size_t)b * T_ + t0) * 2;
        *(float4*)(wgt + wb)      = *(float4*)(w);
        *(float4*)(wgt + wb + 4)  = *(float4*)(w + 4);
        *(float4*)(wgt + wb + 8)  = *(float4*)(w + 8);
        *(float4*)(wgt + wb + 12) = *(float4*)(w + 12);
    }

    const int lane = tid & 63, wave = tid >> 6;
    int inc = cnt;
    #pragma unroll
    for (int d = 1; d < 64; d <<= 1) {
        int v = __shfl_up(inc, d);
        if (lane >= d) inc += v;
    }
    __shared__ int wsum[4];
    if (lane == 63) wsum[wave] = inc;
    __syncthreads();
    int waveoff = 0;
    for (int w2 = 0; w2 < wave; ++w2) waveoff += wsum[w2];
    int r = waveoff + inc - cnt;
    #pragma unroll
    for (int j = 0; j < 8; ++j) {
        if (fr[j]) {
            if (r < Lpad) fire_pos[b * Lpad + r] = t0 + j;
            ++r;
        }
    }
    if (tid == 255) n_fires[b] = waveoff + inc;

    float s = asum;
    #pragma unroll
    for (int m = 32; m; m >>= 1) s += __shfl_xor(s, m);
    __shared__ float wred[4];
    if (lane == 0) wred[wave] = s;
    __syncthreads();
    if (tid == 0) cif_length[b] = wred[0] + wred[1] + wred[2] + wred[3];
}

// ---------------------------------------------------------------------------
// K3: gather/emit. MEASUREMENT ROUND: streaming body repeated K3REP times.
// ---------------------------------------------------------------------------
__global__ __launch_bounds__(256) void k3_frames(
    const float* __restrict__ hidden, const float* __restrict__ wgt,
    const int* __restrict__ fire_pos, const int* __restrict__ n_fires,
    float* __restrict__ out, int L, int Lpad)
{
    const int k0 = blockIdx.x * KPB;
    const int b  = blockIdx.y;
    const int tid = threadIdx.x;
    const int h0 = tid * 4;
    const size_t hb = ((size_t)b * T_) * H_ + h0;
    const float2* wb = (const float2*)wgt + (size_t)b * T_;

    const int n = __builtin_amdgcn_readfirstlane(n_fires[b]);
    const int kmax = min(KPB, L - k0);
    const int kact = min(kmax, n - k0);

    const float4 zero4 = make_float4(0.f, 0.f, 0.f, 0.f);
    if (kact <= 0) {
        #pragma unroll 1
        for (int rep = 0; rep < K3REP; ++rep) {
            for (int kk = 0; kk < kmax; ++kk)
                ntstore4(out + ((size_t)b * L + (k0 + kk)) * H_ + h0, zero4);
            asm volatile("" ::: "memory");
        }
        return;
    }

    const int tend = __builtin_amdgcn_readfirstlane(fire_pos[b * Lpad + k0 + kact - 1]);
    int s0 = -1;
    if (k0 > 0) s0 = __builtin_amdgcn_readfirstlane(fire_pos[b * Lpad + k0 - 1]);

    #pragma unroll 1
    for (int rep = 0; rep < K3REP; ++rep) {
        float4 acc;
        int t;
        if (k0 > 0) {
            const float4 hr = *(const float4*)(hidden + hb + (size_t)s0 * H_);
            const float rm = wb[s0].y;
            acc.x = rm * hr.x; acc.y = rm * hr.y; acc.z = rm * hr.z; acc.w = rm * hr.w;
            t = s0 + 1;
        } else {
            acc = zero4;
            t = 0;
        }

        float4 hA, hB, hC, hD;
        float2 wA, wB, wC, wD;
        hA = *(const float4*)(hidden + hb + (size_t)t * H_);
        wA = wb[t];
        if (t + 1 <= tend) {
            hB = *(const float4*)(hidden + hb + (size_t)(t + 1) * H_);
            wB = wb[t + 1];
        } else { hB = zero4; wB = make_float2(0.f, -1.f); }
        if (t + 2 <= tend) {
            hC = *(const float4*)(hidden + hb + (size_t)(t + 2) * H_);
            wC = wb[t + 2];
        } else { hC = zero4; wC = make_float2(0.f, -1.f); }

        int kk = 0;
        while (t <= tend) {
            if (t + 3 <= tend) {
                hD = *(const float4*)(hidden + hb + (size_t)(t + 3) * H_);
                wD = wb[t + 3];
            } else { hD = zero4; wD = make_float2(0.f, -1.f); }

            acc.x = fmaf(wA.x, hA.x, acc.x);
            acc.y = fmaf(wA.x, hA.y, acc.y);
            acc.z = fmaf(wA.x, hA.z, acc.z);
            acc.w = fmaf(wA.x, hA.w, acc.w);
            if (wA.y >= 0.f) {
                ntstore4(out + ((size_t)b * L + (k0 + kk)) * H_ + h0, acc);
                acc.x = wA.y * hA.x; acc.y = wA.y * hA.y;
                acc.z = wA.y * hA.z; acc.w = wA.y * hA.w;
                ++kk;
            }
            hA = hB; wA = wB; hB = hC; wB = wC; hC = hD; wC = wD;
            ++t;
        }

        for (; kk < kmax; ++kk)
            ntstore4(out + ((size_t)b * L + (k0 + kk)) * H_ + h0, zero4);
        asm volatile("" ::: "memory");
    }
}

extern "C" void kernel_launch(void* const* d_in, const int* in_sizes, int n_in,
                              void* d_out, int out_size, void* d_ws, size_t ws_size,
                              hipStream_t stream) {
    const float* hidden = (const float*)d_in[0];
    const float* conv_w = (const float*)d_in[1];
    const float* conv_b = (const float*)d_in[2];
    const float* lin_w  = (const float*)d_in[3];
    const float* lin_b  = (const float*)d_in[4];
    float* out = (float*)d_out;

    const int L = (out_size - B_ - B_ * T_) / (B_ * H_);
    float* cif_output = out;
    float* cif_length = out + (size_t)B_ * L * H_;
    float* fires      = cif_length + B_;

    float* alphas = (float*)d_ws;
    float* wgt    = alphas + (size_t)B_ * T_;
    const int Lpad = L + 8;
    int* fire_pos = (int*)(wgt + (size_t)2 * B_ * T_);
    int* n_fires  = fire_pos + (size_t)B_ * Lpad;

    k1_alphas<<<dim3(B_ * (T_ / TPB)), 256, 0, stream>>>(
        hidden, conv_w, conv_b, lin_w, lin_b, alphas);
    k2_scan_coef<<<dim3(B_), 256, 0, stream>>>(
        alphas, fires, wgt, fire_pos, n_fires, cif_length, Lpad);
    k3_frames<<<dim3((L + KPB - 1) / KPB, B_), 256, 0, stream>>>(
        hidden, wgt, fire_pos, n_fires, cif_output, L, Lpad);
}

// Round 6
// 259.663 us; speedup vs baseline: 2.0443x; 2.0443x over previous
//
#include <hip/hip_runtime.h>
#include <math.h>

#define B_ 16
#define T_ 2048
#define H_ 1024
#define TPB 32   // t-rows per block in k1
#define KPB 8    // output rows per block in k3

typedef float f32x4_t __attribute__((ext_vector_type(4)));

__device__ __forceinline__ void ntstore4(float* p, float4 v) {
    f32x4_t w = { v.x, v.y, v.z, v.w };
    __builtin_nontemporal_store(w, (f32x4_t*)p);
}

// ---------------------------------------------------------------------------
// K1: alphas = sigmoid(sum_h relu(conv+bias+x) * lin_w + lin_b)
// At its BW floor (~23 us, measured R5: warm reps 8 us, cold 23 us = 144 MB
// compulsory HBM read). Depth-4 prefetch ring, TPB=32.
// ---------------------------------------------------------------------------
__global__ __launch_bounds__(256) void k1_alphas(
    const float* __restrict__ hidden, const float* __restrict__ conv_w,
    const float* __restrict__ conv_b, const float* __restrict__ lin_w,
    const float* __restrict__ lin_b, float* __restrict__ alphas)
{
    const int tile = blockIdx.x & (T_ / TPB - 1);
    const int b    = blockIdx.x / (T_ / TPB);
    const int tid  = threadIdx.x;
    const int h0   = tid * 4;

    float w0[4], w1[4], w2[4];
    {
        const float4* cw = (const float4*)(conv_w + (size_t)h0 * 3);
        float4 c0 = cw[0], c1 = cw[1], c2 = cw[2];
        w0[0] = c0.x; w1[0] = c0.y; w2[0] = c0.z;
        w0[1] = c0.w; w1[1] = c1.x; w2[1] = c1.y;
        w0[2] = c1.z; w1[2] = c1.w; w2[2] = c2.x;
        w0[3] = c2.y; w1[3] = c2.z; w2[3] = c2.w;
    }
    const float4 cb = *(const float4*)(conv_b + h0);
    const float4 lw = *(const float4*)(lin_w + h0);
    const float  lb = lin_b[0];

    const size_t base = ((size_t)b * T_) * H_ + h0;
    const int t0 = tile * TPB;
    const float4 zero4 = make_float4(0.f, 0.f, 0.f, 0.f);

    float4 prev = (t0 > 0) ? *(const float4*)(hidden + base + (size_t)(t0 - 1) * H_)
                           : zero4;
    float4 curr = *(const float4*)(hidden + base + (size_t)t0 * H_);
    float4 buf0 = *(const float4*)(hidden + base + (size_t)(t0 + 1) * H_);
    float4 buf1 = *(const float4*)(hidden + base + (size_t)(t0 + 2) * H_);
    float4 buf2 = *(const float4*)(hidden + base + (size_t)(t0 + 3) * H_);
    float4 buf3 = *(const float4*)(hidden + base + (size_t)(t0 + 4) * H_);
    // (t0+4 <= T_-TPB+4 = 2020 < T_, preloads always in range)

    __shared__ float lds[4][TPB];
    const int wave = tid >> 6;
    const int lane = tid & 63;

    #pragma unroll
    for (int tt = 0; tt < TPB; ++tt) {
        float4 next;
        const int tp = t0 + tt + 5;
        switch (tt & 3) {
        case 0: next = buf0;
                buf0 = (tp < T_) ? *(const float4*)(hidden + base + (size_t)tp * H_) : zero4;
                break;
        case 1: next = buf1;
                buf1 = (tp < T_) ? *(const float4*)(hidden + base + (size_t)tp * H_) : zero4;
                break;
        case 2: next = buf2;
                buf2 = (tp < T_) ? *(const float4*)(hidden + base + (size_t)tp * H_) : zero4;
                break;
        default: next = buf3;
                buf3 = (tp < T_) ? *(const float4*)(hidden + base + (size_t)tp * H_) : zero4;
                break;
        }

        float p = 0.f, v;
        v = fmaf(w0[0], prev.x, fmaf(w1[0], curr.x, fmaf(w2[0], next.x, cb.x + curr.x)));
        p = fmaf(fmaxf(v, 0.f), lw.x, p);
        v = fmaf(w0[1], prev.y, fmaf(w1[1], curr.y, fmaf(w2[1], next.y, cb.y + curr.y)));
        p = fmaf(fmaxf(v, 0.f), lw.y, p);
        v = fmaf(w0[2], prev.z, fmaf(w1[2], curr.z, fmaf(w2[2], next.z, cb.z + curr.z)));
        p = fmaf(fmaxf(v, 0.f), lw.z, p);
        v = fmaf(w0[3], prev.w, fmaf(w1[3], curr.w, fmaf(w2[3], next.w, cb.w + curr.w)));
        p = fmaf(fmaxf(v, 0.f), lw.w, p);
        #pragma unroll
        for (int m = 32; m; m >>= 1) p += __shfl_xor(p, m);
        if (lane == 0) lds[wave][tt] = p;
        prev = curr; curr = next;
    }
    __syncthreads();
    if (tid < TPB) {
        float s = lds[0][tid] + lds[1][tid] + lds[2][tid] + lds[3][tid] + lb;
        alphas[(size_t)b * T_ + t0 + tid] = 1.f / (1.f + expf(-s));
    }
}

// ---------------------------------------------------------------------------
// K2 (fused scan+coef): one block per batch.
// Phase 2 REWRITTEN (the R5-measured ~80 us hotspot): the serial chain now
// uses ds_read_b128-vectorized, double-buffered register groups. Per 16-elem
// group: issue 4 vector loads of group g+1, run the 16-step register-only
// add/fract chain of group g (covers the ~120cy LDS latency), then 4 vector
// stores of f. The op sequence on I is IDENTICAL to before -> bit-exact.
// ---------------------------------------------------------------------------
__global__ __launch_bounds__(256) void k2_scan_coef(
    const float* __restrict__ alphas, float* __restrict__ fires,
    float* __restrict__ wgt,
    int* __restrict__ fire_pos, int* __restrict__ n_fires,
    float* __restrict__ cif_length, int Lpad)
{
    const int b = blockIdx.x;
    const int tid = threadIdx.x;
    const size_t base = (size_t)b * T_;

    __shared__ float sA[T_];  // 8 KB
    __shared__ float sF[T_];  // 8 KB

    // Phase 1: stage alphas
    {
        const int i = tid * 8;  // 256*8 = 2048 = T_
        *(float4*)(sA + i)     = *(const float4*)(alphas + base + i);
        *(float4*)(sA + i + 4) = *(const float4*)(alphas + base + i + 4);
    }
    __syncthreads();

    // Phase 2: serial scan (thread 0), vectorized LDS access + reg chain
    if (tid == 0) {
        float4 a0 = *(const float4*)(sA + 0);
        float4 a1 = *(const float4*)(sA + 4);
        float4 a2 = *(const float4*)(sA + 8);
        float4 a3 = *(const float4*)(sA + 12);
        float I = 0.f;
        for (int t = 0; t < T_; t += 16) {
            const int tn = (t + 16 < T_) ? t + 16 : 0;  // safe dummy on last iter
            float4 b0 = *(const float4*)(sA + tn);
            float4 b1 = *(const float4*)(sA + tn + 4);
            float4 b2 = *(const float4*)(sA + tn + 8);
            float4 b3 = *(const float4*)(sA + tn + 12);

            float4 f0, f1, f2, f3;
            I += a0.x; f0.x = I; I = __builtin_amdgcn_fractf(I);
            I += a0.y; f0.y = I; I = __builtin_amdgcn_fractf(I);
            I += a0.z; f0.z = I; I = __builtin_amdgcn_fractf(I);
            I += a0.w; f0.w = I; I = __builtin_amdgcn_fractf(I);
            I += a1.x; f1.x = I; I = __builtin_amdgcn_fractf(I);
            I += a1.y; f1.y = I; I = __builtin_amdgcn_fractf(I);
            I += a1.z; f1.z = I; I = __builtin_amdgcn_fractf(I);
            I += a1.w; f1.w = I; I = __builtin_amdgcn_fractf(I);
            I += a2.x; f2.x = I; I = __builtin_amdgcn_fractf(I);
            I += a2.y; f2.y = I; I = __builtin_amdgcn_fractf(I);
            I += a2.z; f2.z = I; I = __builtin_amdgcn_fractf(I);
            I += a2.w; f2.w = I; I = __builtin_amdgcn_fractf(I);
            I += a3.x; f3.x = I; I = __builtin_amdgcn_fractf(I);
            I += a3.y; f3.y = I; I = __builtin_amdgcn_fractf(I);
            I += a3.z; f3.z = I; I = __builtin_amdgcn_fractf(I);
            I += a3.w; f3.w = I; I = __builtin_amdgcn_fractf(I);

            *(float4*)(sF + t)      = f0;
            *(float4*)(sF + t + 4)  = f1;
            *(float4*)(sF + t + 8)  = f2;
            *(float4*)(sF + t + 12) = f3;
            a0 = b0; a1 = b1; a2 = b2; a3 = b3;
        }
    }
    __syncthreads();

    // Phase 3: coefficients + fire positions + outputs
    const int t0 = tid * 8;
    float a[8], f[8];
    #pragma unroll
    for (int j = 0; j < 8; ++j) { a[j] = sA[t0 + j]; f[j] = sF[t0 + j]; }
    const float fprev = (t0 == 0) ? 0.f : sF[t0 - 1];

    ntstore4(fires + base + t0,     make_float4(f[0], f[1], f[2], f[3]));
    ntstore4(fires + base + t0 + 4, make_float4(f[4], f[5], f[6], f[7]));

    float w[16];
    bool fr[8];
    float asum = 0.f;
    int cnt = 0;
    #pragma unroll
    for (int j = 0; j < 8; ++j) {
        float fp = (j == 0) ? fprev : f[j - 1];
        float Iprev = __builtin_amdgcn_fractf(fp);
        fr[j] = (f[j] >= 1.f);
        const float dist = 1.f - Iprev;
        const float cu = fr[j] ? dist : a[j];
        const float re = a[j] - cu;
        w[2 * j]     = cu;
        w[2 * j + 1] = fr[j] ? re : -1.f;  // sign = "no fire here"
        cnt += fr[j] ? 1 : 0;
        asum += a[j];
    }
    {
        const size_t wb = ((size_t)b * T_ + t0) * 2;
        *(float4*)(wgt + wb)      = *(float4*)(w);
        *(float4*)(wgt + wb + 4)  = *(float4*)(w + 4);
        *(float4*)(wgt + wb + 8)  = *(float4*)(w + 8);
        *(float4*)(wgt + wb + 12) = *(float4*)(w + 12);
    }

    const int lane = tid & 63, wave = tid >> 6;
    int inc = cnt;
    #pragma unroll
    for (int d = 1; d < 64; d <<= 1) {
        int v = __shfl_up(inc, d);
        if (lane >= d) inc += v;
    }
    __shared__ int wsum[4];
    if (lane == 63) wsum[wave] = inc;
    __syncthreads();
    int waveoff = 0;
    for (int w2 = 0; w2 < wave; ++w2) waveoff += wsum[w2];
    int r = waveoff + inc - cnt;
    #pragma unroll
    for (int j = 0; j < 8; ++j) {
        if (fr[j]) {
            if (r < Lpad) fire_pos[b * Lpad + r] = t0 + j;
            ++r;
        }
    }
    if (tid == 255) n_fires[b] = waveoff + inc;

    float s = asum;
    #pragma unroll
    for (int m = 32; m; m >>= 1) s += __shfl_xor(s, m);
    __shared__ float wred[4];
    if (lane == 0) wred[wave] = s;
    __syncthreads();
    if (tid == 0) cif_length[b] = wred[0] + wred[1] + wred[2] + wred[3];
}

// ---------------------------------------------------------------------------
// K3: gather/emit, KPB output rows per block, LINEAR t-walk with 4-deep
// software pipeline. ~30 us measured (R5), ~1.5x over its BW floor.
// ---------------------------------------------------------------------------
__global__ __launch_bounds__(256) void k3_frames(
    const float* __restrict__ hidden, const float* __restrict__ wgt,
    const int* __restrict__ fire_pos, const int* __restrict__ n_fires,
    float* __restrict__ out, int L, int Lpad)
{
    const int k0 = blockIdx.x * KPB;
    const int b  = blockIdx.y;
    const int tid = threadIdx.x;
    const int h0 = tid * 4;
    const size_t hb = ((size_t)b * T_) * H_ + h0;
    const float2* wb = (const float2*)wgt + (size_t)b * T_;

    const int n = __builtin_amdgcn_readfirstlane(n_fires[b]);
    const int kmax = min(KPB, L - k0);
    const int kact = min(kmax, n - k0);

    const float4 zero4 = make_float4(0.f, 0.f, 0.f, 0.f);
    if (kact <= 0) {
        for (int kk = 0; kk < kmax; ++kk)
            ntstore4(out + ((size_t)b * L + (k0 + kk)) * H_ + h0, zero4);
        return;
    }

    const int tend = __builtin_amdgcn_readfirstlane(fire_pos[b * Lpad + k0 + kact - 1]);

    float4 acc;
    int t;
    if (k0 > 0) {
        const int s0 = __builtin_amdgcn_readfirstlane(fire_pos[b * Lpad + k0 - 1]);
        const float4 hr = *(const float4*)(hidden + hb + (size_t)s0 * H_);
        const float rm = wb[s0].y;  // s0 is a fire row -> .y holds rem >= 0
        acc.x = rm * hr.x; acc.y = rm * hr.y; acc.z = rm * hr.z; acc.w = rm * hr.w;
        t = s0 + 1;
    } else {
        acc = zero4;
        t = 0;
    }

    float4 hA, hB, hC, hD;
    float2 wA, wB, wC, wD;
    hA = *(const float4*)(hidden + hb + (size_t)t * H_);
    wA = wb[t];
    if (t + 1 <= tend) {
        hB = *(const float4*)(hidden + hb + (size_t)(t + 1) * H_);
        wB = wb[t + 1];
    } else { hB = zero4; wB = make_float2(0.f, -1.f); }
    if (t + 2 <= tend) {
        hC = *(const float4*)(hidden + hb + (size_t)(t + 2) * H_);
        wC = wb[t + 2];
    } else { hC = zero4; wC = make_float2(0.f, -1.f); }

    int kk = 0;
    while (t <= tend) {
        if (t + 3 <= tend) {
            hD = *(const float4*)(hidden + hb + (size_t)(t + 3) * H_);
            wD = wb[t + 3];
        } else { hD = zero4; wD = make_float2(0.f, -1.f); }

        acc.x = fmaf(wA.x, hA.x, acc.x);
        acc.y = fmaf(wA.x, hA.y, acc.y);
        acc.z = fmaf(wA.x, hA.z, acc.z);
        acc.w = fmaf(wA.x, hA.w, acc.w);
        if (wA.y >= 0.f) {  // fire: emit row, start next with rem*h
            ntstore4(out + ((size_t)b * L + (k0 + kk)) * H_ + h0, acc);
            acc.x = wA.y * hA.x; acc.y = wA.y * hA.y;
            acc.z = wA.y * hA.z; acc.w = wA.y * hA.w;
            ++kk;
        }
        hA = hB; wA = wB; hB = hC; wB = wC; hC = hD; wC = wD;
        ++t;
    }

    for (; kk < kmax; ++kk)
        ntstore4(out + ((size_t)b * L + (k0 + kk)) * H_ + h0, zero4);
}

extern "C" void kernel_launch(void* const* d_in, const int* in_sizes, int n_in,
                              void* d_out, int out_size, void* d_ws, size_t ws_size,
                              hipStream_t stream) {
    const float* hidden = (const float*)d_in[0];
    const float* conv_w = (const float*)d_in[1];
    const float* conv_b = (const float*)d_in[2];
    const float* lin_w  = (const float*)d_in[3];
    const float* lin_b  = (const float*)d_in[4];
    float* out = (float*)d_out;

    // out = [cif_output B*L*H | cif_length B | fires B*T]
    const int L = (out_size - B_ - B_ * T_) / (B_ * H_);
    float* cif_output = out;
    float* cif_length = out + (size_t)B_ * L * H_;
    float* fires      = cif_length + B_;

    // workspace: alphas (B*T) + wgt (2*B*T) + fire_pos + n_fires
    float* alphas = (float*)d_ws;
    float* wgt    = alphas + (size_t)B_ * T_;
    const int Lpad = L + 8;
    int* fire_pos = (int*)(wgt + (size_t)2 * B_ * T_);
    int* n_fires  = fire_pos + (size_t)B_ * Lpad;

    k1_alphas<<<dim3(B_ * (T_ / TPB)), 256, 0, stream>>>(
        hidden, conv_w, conv_b, lin_w, lin_b, alphas);
    k2_scan_coef<<<dim3(B_), 256, 0, stream>>>(
        alphas, fires, wgt, fire_pos, n_fires, cif_length, Lpad);
    k3_frames<<<dim3((L + KPB - 1) / KPB, B_), 256, 0, stream>>>(
        hidden, wgt, fire_pos, n_fires, cif_output, L, Lpad);
}